// Round 7
// baseline (485.555 us; speedup 1.0000x reference)
//
#include <hip/hip_runtime.h>
#include <hip/hip_bf16.h>

// Problem constants
#define BATCH 2
#define SEQ   2048
#define HID_  2048
#define NH_   16
#define HD_   128

typedef __bf16 bf16x8 __attribute__((ext_vector_type(8)));
typedef float  f32x4  __attribute__((ext_vector_type(4)));

__device__ __forceinline__ unsigned short f32_to_bf16(float f) {
    unsigned int u = __builtin_bit_cast(unsigned int, f);
    unsigned int r = (u + 0x7fffu + ((u >> 16) & 1u)) >> 16;
    return (unsigned short)r;
}

// async global->LDS, 16 bytes per lane. lds = WAVE-UNIFORM base; HW writes
// lane i at lds + i*16. g is the per-lane global source.
__device__ __forceinline__ void gld_lds16(void* lds, const void* g) {
    __builtin_amdgcn_global_load_lds(
        (const __attribute__((address_space(1))) unsigned int*)g,
        (__attribute__((address_space(3))) unsigned int*)lds, 16, 0, 0);
}

// ---------------------------------------------------------------------------
// fp32 -> bf16 conversion, 4 elements / thread
// ---------------------------------------------------------------------------
__global__ void cvt_f32_bf16(const float* __restrict__ in,
                             unsigned short* __restrict__ out, int n4) {
    int i = blockIdx.x * blockDim.x + threadIdx.x;
    if (i >= n4) return;
    float4 a = reinterpret_cast<const float4*>(in)[i];
    ushort4 o;
    o.x = f32_to_bf16(a.x);
    o.y = f32_to_bf16(a.y);
    o.z = f32_to_bf16(a.z);
    o.w = f32_to_bf16(a.w);
    reinterpret_cast<ushort4*>(out)[i] = o;
}

// ---------------------------------------------------------------------------
// 256x256 8-phase GEMM (HK/m201 template, plain HIP).
// C[M,N] = A[M,K=2048] * B[N,K=2048]^T + bias, bf16 in, fp32 acc.
// 512 thr = 8 waves (2M x 4N, interleaved 16-row/16-col frags).
// LDS: A,B tiles [256][64] bf16, double-buffered (128 KiB), 16B-slot
// XOR-swizzle: phys_slot = logical_slot ^ (row & 7), both sides.
// Per 8-phase iter: 2 K-tiles; per phase: ds_read subtile + 1 half-tile
// stage (2x gld_lds) + barrier + lgkmcnt(0) + setprio(1) 16 MFMA + vmcnt(4)
// only at phases 4/8.  MODE 0: QKV epilogue (Q,K bf16; V^T scatter);
// MODE 2: fp32 out.
// ---------------------------------------------------------------------------
template <int MODE>
__global__ __launch_bounds__(512, 2)
void gemm256(const unsigned short* __restrict__ A,
             const unsigned short* __restrict__ B,
             const float* __restrict__ bq,
             const float* __restrict__ bk,
             const float* __restrict__ bv,
             unsigned short* __restrict__ Qo,
             unsigned short* __restrict__ Ko,
             unsigned short* __restrict__ Vto,
             float* __restrict__ Fo) {
    const int K = 2048;
    const int NT = 32;                 // K / 64

    __shared__ unsigned short Asm[2][256 * 64];   // 64 KiB
    __shared__ unsigned short Bsm[2][256 * 64];   // 64 KiB

    const int tid  = threadIdx.x;
    const int lane = tid & 63;
    const int w    = tid >> 6;         // wave 0..7
    const int wm   = w >> 2;           // 0..1
    const int wn   = w & 3;            // 0..3
    const int l16  = lane & 15;
    const int l4   = lane >> 4;
    const int rkey = l16 & 7;          // read-side swizzle key = row&7

    const int row0 = blockIdx.y * 256;
    const int col0 = blockIdx.x * 256;

    // staging: lane covers row (lane>>3), phys slot (lane&7); source column
    // pre-swizzled so linear LDS holds the swizzled layout.
    const int srow8 = lane >> 3;                   // row&7 at stage time
    const int scol  = ((lane & 7) ^ srow8) * 8;    // swizzled src col (elems)
    const unsigned short* Agb = A + (size_t)(row0 + w * 16 + srow8) * K + scol;
    const unsigned short* Bgb = B + (size_t)(col0 + w * 16 + srow8) * K + scol;

#define STAGE_A(bb, h, kt) do { \
    gld_lds16(&Asm[bb][((h) * 128 + w * 16 + 0) * 64], \
              Agb + (size_t)((h) * 128 + 0) * K + (kt) * 64); \
    gld_lds16(&Asm[bb][((h) * 128 + w * 16 + 8) * 64], \
              Agb + (size_t)((h) * 128 + 8) * K + (kt) * 64); \
  } while (0)
#define STAGE_B(bb, h, kt) do { \
    gld_lds16(&Bsm[bb][((h) * 128 + w * 16 + 0) * 64], \
              Bgb + (size_t)((h) * 128 + 0) * K + (kt) * 64); \
    gld_lds16(&Bsm[bb][((h) * 128 + w * 16 + 8) * 64], \
              Bgb + (size_t)((h) * 128 + 8) * K + (kt) * 64); \
  } while (0)

    // frag reads: A row = wm*16 + j*32 + l16 ; B row = wn*16 + jn*64 + l16
#define LDA(dst, bb, j, kk) dst = *reinterpret_cast<const bf16x8*>( \
    &Asm[bb][(wm * 16 + (j) * 32 + l16) * 64 + ((((kk) * 4 + l4) ^ rkey) * 8)])
#define LDB(dst, bb, jn, kk) dst = *reinterpret_cast<const bf16x8*>( \
    &Bsm[bb][(wn * 16 + (jn) * 64 + l16) * 64 + ((((kk) * 4 + l4) ^ rkey) * 8)])

    f32x4 acc[8][4] = {};
    bf16x8 a[4][2], b[2][2];

#define MM(i, j, kk) acc[i][j] = __builtin_amdgcn_mfma_f32_16x16x32_bf16( \
    a[(i) & 3][kk], b[(j) & 1][kk], acc[i][j], 0, 0, 0)

#define PH(qm, qn, bb, LA, LB, STG, VM) do { \
    if (LA) { \
        LDA(a[0][0], bb, (qm) * 4 + 0, 0); LDA(a[0][1], bb, (qm) * 4 + 0, 1); \
        LDA(a[1][0], bb, (qm) * 4 + 1, 0); LDA(a[1][1], bb, (qm) * 4 + 1, 1); \
        LDA(a[2][0], bb, (qm) * 4 + 2, 0); LDA(a[2][1], bb, (qm) * 4 + 2, 1); \
        LDA(a[3][0], bb, (qm) * 4 + 3, 0); LDA(a[3][1], bb, (qm) * 4 + 3, 1); \
    } \
    if (LB) { \
        LDB(b[0][0], bb, (qn) * 2 + 0, 0); LDB(b[0][1], bb, (qn) * 2 + 0, 1); \
        LDB(b[1][0], bb, (qn) * 2 + 1, 0); LDB(b[1][1], bb, (qn) * 2 + 1, 1); \
    } \
    STG; \
    __builtin_amdgcn_s_barrier(); \
    asm volatile("s_waitcnt lgkmcnt(0)" ::: "memory"); \
    __builtin_amdgcn_s_setprio(1); \
    MM((qm) * 4 + 0, (qn) * 2 + 0, 0); MM((qm) * 4 + 0, (qn) * 2 + 0, 1); \
    MM((qm) * 4 + 0, (qn) * 2 + 1, 0); MM((qm) * 4 + 0, (qn) * 2 + 1, 1); \
    MM((qm) * 4 + 1, (qn) * 2 + 0, 0); MM((qm) * 4 + 1, (qn) * 2 + 0, 1); \
    MM((qm) * 4 + 1, (qn) * 2 + 1, 0); MM((qm) * 4 + 1, (qn) * 2 + 1, 1); \
    MM((qm) * 4 + 2, (qn) * 2 + 0, 0); MM((qm) * 4 + 2, (qn) * 2 + 0, 1); \
    MM((qm) * 4 + 2, (qn) * 2 + 1, 0); MM((qm) * 4 + 2, (qn) * 2 + 1, 1); \
    MM((qm) * 4 + 3, (qn) * 2 + 0, 0); MM((qm) * 4 + 3, (qn) * 2 + 0, 1); \
    MM((qm) * 4 + 3, (qn) * 2 + 1, 0); MM((qm) * 4 + 3, (qn) * 2 + 1, 1); \
    __builtin_amdgcn_s_setprio(0); \
    VM; \
    __builtin_amdgcn_s_barrier(); \
  } while (0)

    // ---- prologue: tile0 (A0,B1,A1,B0) + tile1 (A0,B1); wait; barrier ----
    STAGE_A(0, 0, 0); STAGE_B(0, 1, 0); STAGE_A(0, 1, 0); STAGE_B(0, 0, 0);
    STAGE_A(1, 0, 1); STAGE_B(1, 1, 1);
    asm volatile("s_waitcnt vmcnt(4)" ::: "memory");
    __builtin_amdgcn_s_barrier();

    // ---- main loop: 16 iters x 8 phases, 2 K-tiles/iter ----
    for (int i = 0; i < 16; ++i) {
        const int t  = 2 * i;
        const bool s2 = (t + 2) < NT;
        const bool s3 = (t + 3) < NT;
        // tile t (buf0) quadrants; stage t+1 tail / t+2 head
        PH(0, 0, 0, 1, 1, { STAGE_A(1, 1, t + 1); }, );
        PH(0, 1, 0, 0, 1, { STAGE_B(1, 0, t + 1); }, );
        PH(1, 1, 0, 1, 0, { if (s2) STAGE_A(0, 0, t + 2); }, );
        PH(1, 0, 0, 0, 1, { if (s2) STAGE_B(0, 1, t + 2); },
           { if (i == 15) asm volatile("s_waitcnt vmcnt(0)" ::: "memory");
             else         asm volatile("s_waitcnt vmcnt(4)" ::: "memory"); });
        // tile t+1 (buf1) quadrants; stage t+2 tail / t+3 head
        PH(0, 0, 1, 1, 1, { if (s2) STAGE_A(0, 1, t + 2); }, );
        PH(0, 1, 1, 0, 1, { if (s2) STAGE_B(0, 0, t + 2); }, );
        PH(1, 1, 1, 1, 0, { if (s3) STAGE_A(1, 0, t + 3); }, );
        PH(1, 0, 1, 0, 1, { if (s3) STAGE_B(1, 1, t + 3); },
           { if (i < 15)  asm volatile("s_waitcnt vmcnt(4)" ::: "memory"); });
    }
    asm volatile("s_waitcnt vmcnt(0)" ::: "memory");

    // ---- epilogue ----
    const int seg = col0 >> 11;   // MODE 0: 0=Q 1=K 2=V (256 | 2048)
    const float* bias = (MODE == 2) ? bq : (seg == 0 ? bq : (seg == 1 ? bk : bv));
#pragma unroll
    for (int jn = 0; jn < 4; ++jn) {
        const int col  = col0 + wn * 16 + jn * 64 + l16;
        const int lcol = col & (HID_ - 1);
        const float bvv = bias[lcol];
#pragma unroll
        for (int j = 0; j < 8; ++j) {
#pragma unroll
            for (int rr = 0; rr < 4; ++rr) {
                const int row = row0 + wm * 16 + j * 32 + l4 * 4 + rr;
                const float v = acc[j][jn][rr] + bvv;
                if (MODE == 2) {
                    Fo[(size_t)row * HID_ + col] = v;
                } else if (seg == 0) {
                    Qo[(size_t)row * HID_ + lcol] = f32_to_bf16(v);
                } else if (seg == 1) {
                    Ko[(size_t)row * HID_ + lcol] = f32_to_bf16(v);
                } else {
                    const int b2 = row >> 11, s = row & (SEQ - 1);
                    const int hh = lcol >> 7, d = lcol & (HD_ - 1);
                    Vto[((size_t)((b2 * NH_ + hh) * HD_ + d)) * SEQ + s] =
                        f32_to_bf16(v);
                }
            }
        }
    }
#undef STAGE_A
#undef STAGE_B
#undef LDA
#undef LDB
#undef MM
#undef PH
}

// ---------------------------------------------------------------------------
// Causal flash attention (round-5 version, unchanged): cooperative 4-wave
// blocks, 64 q rows / block; K/V^T tiles double-buffered in LDS via
// global_load_lds, XOR-swizzled; grid (B*NH, SEQ/64), heavy-first LPT.
// ---------------------------------------------------------------------------
__global__ __launch_bounds__(256, 2)
void attn_fwd(const unsigned short* __restrict__ Qm,
              const unsigned short* __restrict__ Km,
              const unsigned short* __restrict__ Vt,
              unsigned short* __restrict__ Om) {
    const int tid  = threadIdx.x;
    const int lane = tid & 63;
    const int wq   = tid >> 6;
    const int l16  = lane & 15;
    const int l4   = lane >> 4;

    const int bh = blockIdx.x;
    const int qt = (int)gridDim.y - 1 - (int)blockIdx.y;
    const int b  = bh >> 4;
    const int h  = bh & (NH_ - 1);

    const int qbase  = qt * 64 + wq * 16;
    const int ntiles = qt + 1;

    __shared__ unsigned short Ks[2][64 * 128];
    __shared__ unsigned short Vs[2][128 * 64];
    __shared__ unsigned short plds[4][16][68];

    const unsigned short* Kbh = Km + ((size_t)b * SEQ) * HID_ + h * HD_;
    const unsigned short* Vbh = Vt + (size_t)bh * HD_ * SEQ;

    auto stage = [&](int buf, int t) {
        const int kv0 = t * 64;
        {
            const int rl = lane >> 4;
            const int ck = lane & 15;
#pragma unroll
            for (int j = 0; j < 4; ++j) {
                const int r  = wq * 16 + 4 * j + rl;
                const int lc = ck ^ (r & 7);
                gld_lds16(&Ks[buf][(wq * 16 + 4 * j) * 128],
                          Kbh + (size_t)(kv0 + r) * HID_ + lc * 8);
            }
        }
        {
            const int rl = lane >> 3;
            const int ck = lane & 7;
#pragma unroll
            for (int j = 0; j < 4; ++j) {
                const int r  = wq * 32 + 8 * j + rl;
                const int lc = ck ^ (r & 7);
                gld_lds16(&Vs[buf][(wq * 32 + 8 * j) * 64],
                          Vbh + (size_t)r * SEQ + kv0 + lc * 8);
            }
        }
    };

    stage(0, 0);
    const unsigned short* Qbase =
        Qm + ((size_t)(b * SEQ + qbase + l16)) * HID_ + h * HD_ + l4 * 8;
    bf16x8 qf[4];
#pragma unroll
    for (int kb = 0; kb < 4; ++kb)
        qf[kb] = *reinterpret_cast<const bf16x8*>(Qbase + kb * 32);

    float mrow[4], lrow[4];
#pragma unroll
    for (int r = 0; r < 4; ++r) { mrow[r] = -__builtin_inff(); lrow[r] = 0.f; }
    f32x4 acc[8] = {};

    const float scale = 0.08838834764831845f;  // 1/sqrt(128)

    int buf = 0;
    for (int t = 0; t < ntiles; ++t) {
        __syncthreads();
        if (t + 1 < ntiles) stage(buf ^ 1, t + 1);

        const unsigned short* Kb0 = &Ks[buf][0];
        const unsigned short* Vb0 = &Vs[buf][0];
        const int kv0 = t * 64;
        const int sw  = l16 & 7;

        f32x4 sc[4];
#pragma unroll
        for (int ct = 0; ct < 4; ++ct) {
            f32x4 c = {};
#pragma unroll
            for (int kb = 0; kb < 4; ++kb) {
                bf16x8 kf = *reinterpret_cast<const bf16x8*>(
                    Kb0 + (ct * 16 + l16) * 128 + ((kb * 4 + l4) ^ sw) * 8);
                c = __builtin_amdgcn_mfma_f32_16x16x32_bf16(qf[kb], kf, c, 0, 0, 0);
            }
            sc[ct] = c;
        }

        if (t == ntiles - 1) {
#pragma unroll
            for (int ct = 0; ct < 4; ++ct) {
                const int col = kv0 + ct * 16 + l16;
#pragma unroll
                for (int r = 0; r < 4; ++r) {
                    float v = sc[ct][r] * scale;
                    const int qrow = qbase + l4 * 4 + r;
                    if (col > qrow) v = -__builtin_inff();
                    sc[ct][r] = v;
                }
            }
        } else {
#pragma unroll
            for (int ct = 0; ct < 4; ++ct)
#pragma unroll
                for (int r = 0; r < 4; ++r)
                    sc[ct][r] *= scale;
        }

        float tmax[4];
#pragma unroll
        for (int r = 0; r < 4; ++r) {
            float v = fmaxf(fmaxf(sc[0][r], sc[1][r]), fmaxf(sc[2][r], sc[3][r]));
#pragma unroll
            for (int off = 8; off >= 1; off >>= 1)
                v = fmaxf(v, __shfl_xor(v, off, 64));
            tmax[r] = v;
        }

        float alpha[4], rs[4];
#pragma unroll
        for (int r = 0; r < 4; ++r) {
            const float mn = fmaxf(mrow[r], tmax[r]);
            alpha[r] = __expf(mrow[r] - mn);
            mrow[r] = mn;
            rs[r] = 0.f;
        }

#pragma unroll
        for (int ct = 0; ct < 4; ++ct) {
#pragma unroll
            for (int r = 0; r < 4; ++r) {
                const float p = __expf(sc[ct][r] - mrow[r]);
                rs[r] += p;
                plds[wq][l4 * 4 + r][ct * 16 + l16] = f32_to_bf16(p);
            }
        }

#pragma unroll
        for (int r = 0; r < 4; ++r) {
#pragma unroll
            for (int off = 8; off >= 1; off >>= 1)
                rs[r] += __shfl_xor(rs[r], off, 64);
            lrow[r] = lrow[r] * alpha[r] + rs[r];
        }

#pragma unroll
        for (int dt = 0; dt < 8; ++dt)
#pragma unroll
            for (int r = 0; r < 4; ++r)
                acc[dt][r] *= alpha[r];

        asm volatile("s_waitcnt lgkmcnt(0)" ::: "memory");
        bf16x8 pf[2];
#pragma unroll
        for (int ks = 0; ks < 2; ++ks)
            pf[ks] = *reinterpret_cast<const bf16x8*>(&plds[wq][l16][ks * 32 + l4 * 8]);
#pragma unroll
        for (int dt = 0; dt < 8; ++dt) {
#pragma unroll
            for (int ks = 0; ks < 2; ++ks) {
                bf16x8 vf = *reinterpret_cast<const bf16x8*>(
                    Vb0 + (dt * 16 + l16) * 64 + ((ks * 4 + l4) ^ sw) * 8);
                acc[dt] = __builtin_amdgcn_mfma_f32_16x16x32_bf16(pf[ks], vf, acc[dt], 0, 0, 0);
            }
        }

        buf ^= 1;
    }

    unsigned short* Ob = Om + ((size_t)(b * SEQ + qbase)) * HID_ + h * HD_;
#pragma unroll
    for (int dt = 0; dt < 8; ++dt) {
#pragma unroll
        for (int r = 0; r < 4; ++r) {
            const int qrow = l4 * 4 + r;
            const float v = acc[dt][r] / lrow[r];
            Ob[(size_t)qrow * HID_ + dt * 16 + l16] = f32_to_bf16(v);
        }
    }
}

// ---------------------------------------------------------------------------
extern "C" void kernel_launch(void* const* d_in, const int* in_sizes, int n_in,
                              void* d_out, int out_size, void* d_ws, size_t ws_size,
                              hipStream_t stream) {
    const float* X  = (const float*)d_in[0];
    const float* Wq = (const float*)d_in[1];
    const float* bq = (const float*)d_in[2];
    const float* Wk = (const float*)d_in[3];
    const float* bk = (const float*)d_in[4];
    const float* Wv = (const float*)d_in[5];
    const float* bv = (const float*)d_in[6];
    const float* Wo = (const float*)d_in[7];
    const float* bo = (const float*)d_in[8];
    float* out = (float*)d_out;

    const size_t MK = (size_t)BATCH * SEQ * HID_;   // 8388608
    const size_t WK = (size_t)HID_ * HID_;          // 4194304

    unsigned short* ws  = (unsigned short*)d_ws;
    unsigned short* Xb  = ws;
    unsigned short* Wqb = Xb  + MK;   // Wq, Wk, Wv contiguous -> fused B
    unsigned short* Wkb = Wqb + WK;
    unsigned short* Wvb = Wkb + WK;
    unsigned short* Wob = Wvb + WK;
    unsigned short* Qb  = Wob + WK;
    unsigned short* Kb  = Qb  + MK;
    unsigned short* Vtb = Kb  + MK;
    unsigned short* AOb = Vtb + MK;

    auto cvt = [&](const float* src, unsigned short* dst, size_t n) {
        int n4 = (int)(n / 4);
        cvt_f32_bf16<<<(n4 + 255) / 256, 256, 0, stream>>>(src, dst, n4);
    };
    cvt(X,  Xb,  MK);
    cvt(Wq, Wqb, WK);
    cvt(Wk, Wkb, WK);
    cvt(Wv, Wvb, WK);
    cvt(Wo, Wob, WK);

    // Fused QKV projection, 256^2 8-phase: grid (6144/256, 4096/256)
    gemm256<0><<<dim3(24, 16), 512, 0, stream>>>(
        Xb, Wqb, bq, bk, bv, Qb, Kb, Vtb, nullptr);

    attn_fwd<<<dim3(BATCH * NH_, SEQ / 64), 256, 0, stream>>>(Qb, Kb, Vtb, AOb);

    // O projection, 256^2 8-phase: grid (2048/256, 4096/256)
    gemm256<2><<<dim3(8, 16), 512, 0, stream>>>(
        AOb, Wob, bo, nullptr, nullptr, nullptr, nullptr, nullptr, out);
}

// Round 14
// 433.202 us; speedup vs baseline: 1.1209x; 1.1209x over previous
//
#include <hip/hip_runtime.h>
#include <hip/hip_bf16.h>

// Problem constants
#define BATCH 2
#define SEQ   2048
#define HID_  2048
#define NH_   16
#define HD_   128

typedef __bf16 bf16x8 __attribute__((ext_vector_type(8)));
typedef float  f32x4  __attribute__((ext_vector_type(4)));

__device__ __forceinline__ unsigned short f32_to_bf16(float f) {
    unsigned int u = __builtin_bit_cast(unsigned int, f);
    unsigned int r = (u + 0x7fffu + ((u >> 16) & 1u)) >> 16;
    return (unsigned short)r;
}

// async global->LDS, 16 bytes per lane. lds = WAVE-UNIFORM base; HW writes
// lane i at lds + i*16. g is the per-lane global source.
__device__ __forceinline__ void gld_lds16(void* lds, const void* g) {
    __builtin_amdgcn_global_load_lds(
        (const __attribute__((address_space(1))) unsigned int*)g,
        (__attribute__((address_space(3))) unsigned int*)lds, 16, 0, 0);
}

// ---------------------------------------------------------------------------
// fp32 -> bf16 conversion, 4 elements / thread
// ---------------------------------------------------------------------------
__global__ void cvt_f32_bf16(const float* __restrict__ in,
                             unsigned short* __restrict__ out, int n4) {
    int i = blockIdx.x * blockDim.x + threadIdx.x;
    if (i >= n4) return;
    float4 a = reinterpret_cast<const float4*>(in)[i];
    ushort4 o;
    o.x = f32_to_bf16(a.x);
    o.y = f32_to_bf16(a.y);
    o.z = f32_to_bf16(a.z);
    o.w = f32_to_bf16(a.w);
    reinterpret_cast<ushort4*>(out)[i] = o;
}

// ---------------------------------------------------------------------------
// 128x128 GEMM main loop (prolog + K-loop ONLY; epilogue follows the macro
// as ordinary code — clang forbids #pragma inside macro arguments).
// BK=32, double-buffered LDS (prefetch depth 1), global_load_lds w16,
// counted vmcnt(4) (never a mid-loop drain), both-sides XOR chunk-swizzle
// (phys 16B-chunk = chunk ^ (row&3)).  2 barriers / K-step.
// Block 256 = 4 waves; wave tile 64x64 (4x4 of 16x16 frags).
// Leaves in scope: acc, row0, col0, wr, wc, l16, l4.
// ---------------------------------------------------------------------------
#define GEMM_MAIN_LOOP                                                       \
    const int K = HID_;                                                      \
    const int tid  = threadIdx.x;                                            \
    const int lane = tid & 63;                                               \
    const int wid  = tid >> 6;                                               \
    const int wr   = wid >> 1;                                               \
    const int wc   = wid & 1;                                                \
    const int l16  = lane & 15;                                              \
    const int l4   = lane >> 4;                                              \
    const int ckey = l16 & 3;                                                \
    const int row0 = blockIdx.y * 128;                                       \
    const int col0 = blockIdx.x * 128;                                       \
    __shared__ unsigned short As[2][128 * 32];                               \
    __shared__ unsigned short Bs[2][128 * 32];                               \
    f32x4 acc[4][4] = {};                                                    \
    const int srow = tid >> 2;                                               \
    const int scol = ((tid & 3) ^ (srow & 3)) * 8;  /* pre-swizzled src */   \
    const unsigned short* Ag = A + (size_t)(row0 + srow) * K + scol;         \
    const unsigned short* Bg = B + (size_t)(col0 + srow) * K + scol;         \
    auto stage = [&](int bb, int k0) {                                       \
        gld_lds16(&As[bb][wid * 512],        Ag + k0);                       \
        gld_lds16(&As[bb][2048 + wid * 512], Ag + (size_t)64 * K + k0);      \
        gld_lds16(&Bs[bb][wid * 512],        Bg + k0);                       \
        gld_lds16(&Bs[bb][2048 + wid * 512], Bg + (size_t)64 * K + k0);      \
    };                                                                       \
    stage(0, 0);                                                             \
    int buf = 0;                                                             \
    for (int k0 = 0; k0 < K; k0 += 32) {                                     \
        const bool more = (k0 + 32) < K;                                     \
        if (more) {                                                          \
            stage(buf ^ 1, k0 + 32);                                         \
            asm volatile("s_waitcnt vmcnt(4)" ::: "memory");                 \
        } else {                                                             \
            asm volatile("s_waitcnt vmcnt(0)" ::: "memory");                 \
        }                                                                    \
        __builtin_amdgcn_s_barrier();                                        \
        const unsigned short* Ab = &As[buf][0];                              \
        const unsigned short* Bb = &Bs[buf][0];                              \
        bf16x8 af[4], bfr[4];                                                \
        _Pragma("unroll")                                                    \
        for (int i = 0; i < 4; ++i)                                          \
            af[i] = *reinterpret_cast<const bf16x8*>(                        \
                Ab + (wr * 64 + i * 16 + l16) * 32 + ((l4 ^ ckey) * 8));     \
        _Pragma("unroll")                                                    \
        for (int j = 0; j < 4; ++j)                                          \
            bfr[j] = *reinterpret_cast<const bf16x8*>(                       \
                Bb + (wc * 64 + j * 16 + l16) * 32 + ((l4 ^ ckey) * 8));     \
        _Pragma("unroll")                                                    \
        for (int i = 0; i < 4; ++i)                                          \
            _Pragma("unroll")                                                \
            for (int j = 0; j < 4; ++j)                                      \
                acc[i][j] = __builtin_amdgcn_mfma_f32_16x16x32_bf16(         \
                    af[i], bfr[j], acc[i][j], 0, 0, 0);                      \
        asm volatile("s_waitcnt lgkmcnt(0)" ::: "memory");                   \
        __builtin_amdgcn_s_barrier();                                        \
        buf ^= 1;                                                            \
    }

// Fused QKV: C[M,6144] = X * [Wq;Wk;Wv]^T + bias(seg).  Grid (48, 32).
__global__ __launch_bounds__(256)
void gemm_qkv(const unsigned short* __restrict__ A,
              const unsigned short* __restrict__ B,
              const float* __restrict__ bq,
              const float* __restrict__ bk,
              const float* __restrict__ bv,
              unsigned short* __restrict__ Qo,
              unsigned short* __restrict__ Ko,
              unsigned short* __restrict__ Vto) {
    GEMM_MAIN_LOOP
    // epilogue: segment-uniform (2048 % 128 == 0)
    const int seg = col0 >> 11;                       // 0=Q 1=K 2=V
    const float* bias = (seg == 0) ? bq : (seg == 1) ? bk : bv;
    const int wrow0 = row0 + wr * 64;
    const int wcol0 = (col0 & (HID_ - 1)) + wc * 64;
#pragma unroll
    for (int j = 0; j < 4; ++j) {
        const int col = wcol0 + j * 16 + l16;
        const float bvv = bias[col];
#pragma unroll
        for (int i = 0; i < 4; ++i) {
#pragma unroll
            for (int r = 0; r < 4; ++r) {
                const int row = wrow0 + i * 16 + l4 * 4 + r;
                const float v = acc[i][j][r] + bvv;
                if (seg == 0) {
                    Qo[(size_t)row * HID_ + col] = f32_to_bf16(v);
                } else if (seg == 1) {
                    Ko[(size_t)row * HID_ + col] = f32_to_bf16(v);
                } else {  // V^T: row=(b,s), col=(h,d)
                    const int b = row >> 11, s = row & (SEQ - 1);
                    const int h = col >> 7,  d = col & (HD_ - 1);
                    Vto[((size_t)((b * NH_ + h) * HD_ + d)) * SEQ + s] =
                        f32_to_bf16(v);
                }
            }
        }
    }
}

// O projection: out_f32[M,2048] = A * Wo^T + bo.  Grid (16, 32).
__global__ __launch_bounds__(256)
void gemm_out(const unsigned short* __restrict__ A,
              const unsigned short* __restrict__ B,
              const float* __restrict__ bias,
              float* __restrict__ Cout) {
    GEMM_MAIN_LOOP
    const int wrow0 = row0 + wr * 64;
    const int wcol0 = col0 + wc * 64;
#pragma unroll
    for (int j = 0; j < 4; ++j) {
        const int col = wcol0 + j * 16 + l16;
        const float bv = bias[col];
#pragma unroll
        for (int i = 0; i < 4; ++i) {
#pragma unroll
            for (int r = 0; r < 4; ++r) {
                const int row = wrow0 + i * 16 + l4 * 4 + r;
                Cout[(size_t)row * HID_ + col] = acc[i][j][r] + bv;
            }
        }
    }
}

// ---------------------------------------------------------------------------
// Causal flash attention (round-5 structure + T13 defer-max): cooperative
// 4-wave blocks, 64 q rows / block; K/V^T tiles double-buffered in LDS via
// global_load_lds, XOR-swizzled; grid (B*NH, SEQ/64), heavy-first LPT.
// ---------------------------------------------------------------------------
__global__ __launch_bounds__(256, 2)
void attn_fwd(const unsigned short* __restrict__ Qm,
              const unsigned short* __restrict__ Km,
              const unsigned short* __restrict__ Vt,
              unsigned short* __restrict__ Om) {
    const int tid  = threadIdx.x;
    const int lane = tid & 63;
    const int wq   = tid >> 6;
    const int l16  = lane & 15;
    const int l4   = lane >> 4;

    const int bh = blockIdx.x;
    const int qt = (int)gridDim.y - 1 - (int)blockIdx.y;
    const int b  = bh >> 4;
    const int h  = bh & (NH_ - 1);

    const int qbase  = qt * 64 + wq * 16;
    const int ntiles = qt + 1;

    __shared__ unsigned short Ks[2][64 * 128];
    __shared__ unsigned short Vs[2][128 * 64];
    __shared__ unsigned short plds[4][16][68];

    const unsigned short* Kbh = Km + ((size_t)b * SEQ) * HID_ + h * HD_;
    const unsigned short* Vbh = Vt + (size_t)bh * HD_ * SEQ;

    auto stage = [&](int buf, int t) {
        const int kv0 = t * 64;
        {
            const int rl = lane >> 4;
            const int ck = lane & 15;
#pragma unroll
            for (int j = 0; j < 4; ++j) {
                const int r  = wq * 16 + 4 * j + rl;
                const int lc = ck ^ (r & 7);
                gld_lds16(&Ks[buf][(wq * 16 + 4 * j) * 128],
                          Kbh + (size_t)(kv0 + r) * HID_ + lc * 8);
            }
        }
        {
            const int rl = lane >> 3;
            const int ck = lane & 7;
#pragma unroll
            for (int j = 0; j < 4; ++j) {
                const int r  = wq * 32 + 8 * j + rl;
                const int lc = ck ^ (r & 7);
                gld_lds16(&Vs[buf][(wq * 32 + 8 * j) * 64],
                          Vbh + (size_t)r * SEQ + kv0 + lc * 8);
            }
        }
    };

    stage(0, 0);
    const unsigned short* Qbase =
        Qm + ((size_t)(b * SEQ + qbase + l16)) * HID_ + h * HD_ + l4 * 8;
    bf16x8 qf[4];
#pragma unroll
    for (int kb = 0; kb < 4; ++kb)
        qf[kb] = *reinterpret_cast<const bf16x8*>(Qbase + kb * 32);

    float mrow[4], lrow[4];
#pragma unroll
    for (int r = 0; r < 4; ++r) { mrow[r] = -__builtin_inff(); lrow[r] = 0.f; }
    f32x4 acc[8] = {};

    const float scale = 0.08838834764831845f;  // 1/sqrt(128)

    int buf = 0;
    for (int t = 0; t < ntiles; ++t) {
        __syncthreads();
        if (t + 1 < ntiles) stage(buf ^ 1, t + 1);

        const unsigned short* Kb0 = &Ks[buf][0];
        const unsigned short* Vb0 = &Vs[buf][0];
        const int kv0 = t * 64;
        const int sw  = l16 & 7;

        f32x4 sc[4];
#pragma unroll
        for (int ct = 0; ct < 4; ++ct) {
            f32x4 c = {};
#pragma unroll
            for (int kb = 0; kb < 4; ++kb) {
                bf16x8 kf = *reinterpret_cast<const bf16x8*>(
                    Kb0 + (ct * 16 + l16) * 128 + ((kb * 4 + l4) ^ sw) * 8);
                c = __builtin_amdgcn_mfma_f32_16x16x32_bf16(qf[kb], kf, c, 0, 0, 0);
            }
            sc[ct] = c;
        }

        if (t == ntiles - 1) {
#pragma unroll
            for (int ct = 0; ct < 4; ++ct) {
                const int col = kv0 + ct * 16 + l16;
#pragma unroll
                for (int r = 0; r < 4; ++r) {
                    float v = sc[ct][r] * scale;
                    const int qrow = qbase + l4 * 4 + r;
                    if (col > qrow) v = -__builtin_inff();
                    sc[ct][r] = v;
                }
            }
        } else {
#pragma unroll
            for (int ct = 0; ct < 4; ++ct)
#pragma unroll
                for (int r = 0; r < 4; ++r)
                    sc[ct][r] *= scale;
        }

        float tmax[4];
#pragma unroll
        for (int r = 0; r < 4; ++r) {
            float v = fmaxf(fmaxf(sc[0][r], sc[1][r]), fmaxf(sc[2][r], sc[3][r]));
#pragma unroll
            for (int off = 8; off >= 1; off >>= 1)
                v = fmaxf(v, __shfl_xor(v, off, 64));
            tmax[r] = v;
        }

        // ---- T13 defer-max: rescale only when the max grew by > 8 ----
        bool need = false;
#pragma unroll
        for (int r = 0; r < 4; ++r) need = need || (tmax[r] > mrow[r] + 8.f);
        if (__any(need)) {
#pragma unroll
            for (int r = 0; r < 4; ++r) {
                const float mn = fmaxf(mrow[r], tmax[r]);
                const float al = __expf(mrow[r] - mn);   // 0 on first tile
                mrow[r] = mn;
                lrow[r] *= al;
#pragma unroll
                for (int dt = 0; dt < 8; ++dt)
                    acc[dt][r] *= al;
            }
        }

        float rs[4];
#pragma unroll
        for (int r = 0; r < 4; ++r) rs[r] = 0.f;
#pragma unroll
        for (int ct = 0; ct < 4; ++ct) {
#pragma unroll
            for (int r = 0; r < 4; ++r) {
                const float p = __expf(sc[ct][r] - mrow[r]);   // <= e^8
                rs[r] += p;
                plds[wq][l4 * 4 + r][ct * 16 + l16] = f32_to_bf16(p);
            }
        }

#pragma unroll
        for (int r = 0; r < 4; ++r) {
#pragma unroll
            for (int off = 8; off >= 1; off >>= 1)
                rs[r] += __shfl_xor(rs[r], off, 64);
            lrow[r] += rs[r];
        }

        asm volatile("s_waitcnt lgkmcnt(0)" ::: "memory");
        bf16x8 pf[2];
#pragma unroll
        for (int ks = 0; ks < 2; ++ks)
            pf[ks] = *reinterpret_cast<const bf16x8*>(&plds[wq][l16][ks * 32 + l4 * 8]);
#pragma unroll
        for (int dt = 0; dt < 8; ++dt) {
#pragma unroll
            for (int ks = 0; ks < 2; ++ks) {
                bf16x8 vf = *reinterpret_cast<const bf16x8*>(
                    Vb0 + (dt * 16 + l16) * 64 + ((ks * 4 + l4) ^ sw) * 8);
                acc[dt] = __builtin_amdgcn_mfma_f32_16x16x32_bf16(pf[ks], vf, acc[dt], 0, 0, 0);
            }
        }

        buf ^= 1;
    }

    unsigned short* Ob = Om + ((size_t)(b * SEQ + qbase)) * HID_ + h * HD_;
#pragma unroll
    for (int dt = 0; dt < 8; ++dt) {
#pragma unroll
        for (int r = 0; r < 4; ++r) {
            const int qrow = l4 * 4 + r;
            const float v = acc[dt][r] / lrow[r];
            Ob[(size_t)qrow * HID_ + dt * 16 + l16] = f32_to_bf16(v);
        }
    }
}

// ---------------------------------------------------------------------------
extern "C" void kernel_launch(void* const* d_in, const int* in_sizes, int n_in,
                              void* d_out, int out_size, void* d_ws, size_t ws_size,
                              hipStream_t stream) {
    const float* X  = (const float*)d_in[0];
    const float* Wq = (const float*)d_in[1];
    const float* bq = (const float*)d_in[2];
    const float* Wk = (const float*)d_in[3];
    const float* bk = (const float*)d_in[4];
    const float* Wv = (const float*)d_in[5];
    const float* bv = (const float*)d_in[6];
    const float* Wo = (const float*)d_in[7];
    const float* bo = (const float*)d_in[8];
    float* out = (float*)d_out;

    const size_t MK = (size_t)BATCH * SEQ * HID_;   // 8388608
    const size_t WK = (size_t)HID_ * HID_;          // 4194304

    unsigned short* ws  = (unsigned short*)d_ws;
    unsigned short* Xb  = ws;
    unsigned short* Wqb = Xb  + MK;   // Wq, Wk, Wv contiguous -> fused B
    unsigned short* Wkb = Wqb + WK;
    unsigned short* Wvb = Wkb + WK;
    unsigned short* Wob = Wvb + WK;
    unsigned short* Qb  = Wob + WK;
    unsigned short* Kb  = Qb  + MK;
    unsigned short* Vtb = Kb  + MK;
    unsigned short* AOb = Vtb + MK;

    auto cvt = [&](const float* src, unsigned short* dst, size_t n) {
        int n4 = (int)(n / 4);
        cvt_f32_bf16<<<(n4 + 255) / 256, 256, 0, stream>>>(src, dst, n4);
    };
    cvt(X,  Xb,  MK);
    cvt(Wq, Wqb, WK);
    cvt(Wk, Wkb, WK);
    cvt(Wv, Wvb, WK);
    cvt(Wo, Wob, WK);

    // Fused QKV projection: N = 6144, grid (48, 32) = 1536 blocks
    gemm_qkv<<<dim3(3 * HID_ / 128, BATCH * SEQ / 128), 256, 0, stream>>>(
        Xb, Wqb, bq, bk, bv, Qb, Kb, Vtb);

    attn_fwd<<<dim3(BATCH * NH_, SEQ / 64), 256, 0, stream>>>(Qb, Kb, Vtb, AOb);

    gemm_out<<<dim3(HID_ / 128, BATCH * SEQ / 128), 256, 0, stream>>>(
        AOb, Wob, bo, out);
}